// Round 13
// baseline (228.225 us; speedup 1.0000x reference)
//
#include <hip/hip_runtime.h>

// NODEModel MFMA fp16, R21: clean retest of nt=1 3-waves/SIMD (R19 + bias fix).
// R20 analysis SOLVED the R18/R19 failures: `if (tid<768)` bias copy with 256
// threads left lds_bias[256..767] uninitialized; the ic chain (c==0) reads
// lds_bias[384..511]. At 2 blocks/CU those LDS words happened to be zero
// (= correct, ic biases are zero); at 3 blocks/CU the third LDS base slot
// held stale weight-ring bytes -> garbage bias -> 0.614 / NaN. The nt=1
// occupancy hypothesis was never actually tested -- it was confounded.
// R21 = R19 verbatim + strided bias copy: nt=1 (acc[4]=64 AGPR, bfrag 32,
// 32 samples/wave), launch_bounds(256,3), 2-slot x 16KB ring, spill-robust
// vmcnt(0)+barrier drains at all 7 sync points, tau in-reg H, 32x32x16 MFMA,
// bias/Wout/bout in LDS, out_dot from acc + shfl_xor(32).
// Branches: pass+fast = occupancy hypothesis confirmed; pass+null = kill
// criterion met (R17/R20 is the keeper); WRITE_SIZE balloon = spilled.

#define NTHREADS 256
#define MLP_STRIDE 53248   // fp16 elems per MLP: 4096 WinA + 3*16384 Wh = 13 slabs
#define WINA_ELEMS 4096
#define SLAB_F16 4096      // 8 KB slab
#define TANH_SCALE 2.8853900817779268f   // 2*log2(e)

typedef _Float16 f16;
typedef f16 f16x8 __attribute__((ext_vector_type(8)));
typedef __fp16 fp16x2 __attribute__((ext_vector_type(2)));
typedef float f32x4 __attribute__((ext_vector_type(4)));
typedef float f32x16 __attribute__((ext_vector_type(16)));

// ---------------- prep: fp32 weights -> fp16 fragment-linear (pre-scaled) ----
// Slab layout (8KB): [mt(4)][kh(2)][lane(64)][j(8)] f16;
//   m = 32*mt + (lane&31), k_slot = base + 16*kh + 8*(lane>>5) + j.
// Hidden slabs: weight k-row = tau(k_slot) so next-layer B comes from acc regs.
__global__ __launch_bounds__(NTHREADS)
void prep_kernel(const float* __restrict__ dp_Win, const float* __restrict__ dp_bin,
                 const float* __restrict__ dp_Wh,  const float* __restrict__ dp_bh,
                 const float* __restrict__ ic_Win, const float* __restrict__ ic_bin,
                 const float* __restrict__ ic_Wh,  const float* __restrict__ ic_bh,
                 f16* __restrict__ wsw)
{
    int e = blockIdx.x * NTHREADS + threadIdx.x;
    if (e >= 2 * MLP_STRIDE + 768) return;
    if (e >= 2 * MLP_STRIDE) {          // scaled hidden biases, fp32
        int idx = e - 2 * MLP_STRIDE;   // [mlp(2)][l(3)][m(128)]
        int mlp = idx / 384, rem = idx % 384;
        const float* bh = mlp ? ic_bh : dp_bh;
        float* bsc = (float*)(wsw + 2 * MLP_STRIDE);
        bsc[idx] = bh[rem] * TANH_SCALE;
        return;
    }
    int mlp = (e >= MLP_STRIDE) ? 1 : 0;   // 0 = dp, 1 = ic
    int r = e - mlp * MLP_STRIDE;
    const float* Win = mlp ? ic_Win : dp_Win;
    const float* bin = mlp ? ic_bin : dp_bin;
    const float* Wh  = mlp ? ic_Wh  : dp_Wh;
    int din = mlp ? 5 : 6;
    float val;
    if (r < WINA_ELEMS) {
        int mt = r >> 10, kh = (r >> 9) & 1, lane = (r >> 3) & 63, j = r & 7;
        int m = mt * 32 + (lane & 31);
        int k = kh * 16 + ((lane >> 5) << 3) + j;           // feature index, natural
        val = (k < din) ? Win[k * 128 + m] : ((k == din) ? bin[m] : 0.0f);
    } else {
        int r2 = r - WINA_ELEMS;
        int l = r2 >> 14, r3 = r2 & 16383;
        int ks = r3 >> 12, mt = (r3 >> 10) & 3, kh = (r3 >> 9) & 1;
        int lane = (r3 >> 3) & 63, j = r3 & 7;
        int m = mt * 32 + (lane & 31);
        int k = ks * 32 + kh * 16 + ((lane >> 5) << 3) + j; // slot 0..127
        // tau: slot k=16t+8h'+j' holds prev-layer unit 16t+8*(j'>>2)+4h'+(j'&3)
        int kt = (k & ~15) | (((k & 7) >> 2) << 3) | (((k >> 3) & 1) << 2) | (k & 3);
        val = Wh[(l * 128 + kt) * 128 + m];
    }
    wsw[e] = (f16)(val * TANH_SCALE);
}

// ---------------- main helpers ----------------
__device__ __forceinline__ float tanh_fast(float x) {
    float e = __builtin_amdgcn_exp2f(x);
    float r = __builtin_amdgcn_rcpf(e + 1.0f);
    return fmaf(-2.0f, r, 1.0f);
}

__device__ __forceinline__ unsigned int tanh2_pk(float x0, float x1) {
    float a0 = __builtin_amdgcn_exp2f(x0) + 1.0f;
    float a1 = __builtin_amdgcn_exp2f(x1) + 1.0f;
    float n2 = -2.0f * __builtin_amdgcn_rcpf(a0 * a1);
    union { fp16x2 h; unsigned int u; } c;
    c.h = __builtin_amdgcn_cvt_pkrtz(fmaf(n2, a1, 1.0f), fmaf(n2, a0, 1.0f));
    return c.u;
}

__device__ __forceinline__ f32x16 mfma32(f16x8 a, f16x8 b, f32x16 c) {
    return __builtin_amdgcn_mfma_f32_32x32x16_f16(a, b, c, 0, 0, 0);
}

__device__ __forceinline__ void stage16(const void* g, void* l) {
    __builtin_amdgcn_global_load_lds((const __attribute__((address_space(1))) void*)g,
                                     (__attribute__((address_space(3))) void*)l, 16, 0, 0);
}

__device__ __forceinline__ void stage_slab(const f16* g, unsigned char* dst, int tid) {
    stage16((const char*)g + tid * 16, dst + tid * 16);
    stage16((const char*)g + 4096 + tid * 16, dst + 4096 + tid * 16);
}

__device__ __forceinline__ f16x8 lda(const unsigned char* A, int idx, int lane) {
    return *(const f16x8*)(A + ((idx * 64 + lane) << 4));
}

// drain sync: robust to ANY extra vmem (incl. register spills)
#define SYNC0 do { \
    __asm__ __volatile__("" ::: "memory"); \
    __builtin_amdgcn_s_waitcnt(0x0070); /* vmcnt=0, lgkmcnt=0 */ \
    __builtin_amdgcn_s_barrier(); \
    __asm__ __volatile__("" ::: "memory"); \
} while (0)

__device__ __forceinline__ void frag_build(const f32x16 (&acc)[4], f16x8 (&bf)[4][2]) {
    #pragma unroll
    for (int mt = 0; mt < 4; ++mt)
        #pragma unroll
        for (int kh = 0; kh < 2; ++kh) {
            union { f16x8 f; unsigned u[4]; } w;
            #pragma unroll
            for (int q = 0; q < 4; ++q)
                w.u[q] = tanh2_pk(acc[mt][8 * kh + 2 * q],
                                  acc[mt][8 * kh + 2 * q + 1]);
            bf[mt][kh] = w.f;
        }
}

__device__ __forceinline__ void input_slab(const unsigned char* A, int lane,
                                           const f16x8 bfr, f32x16 (&acc)[4]) {
    const f32x16 z16 = {0.f,0.f,0.f,0.f, 0.f,0.f,0.f,0.f, 0.f,0.f,0.f,0.f, 0.f,0.f,0.f,0.f};
    #pragma unroll
    for (int mt = 0; mt < 4; ++mt) {
        f16x8 a0 = lda(A, mt * 2, lane);
        acc[mt] = mfma32(a0, bfr, z16);
    }
}

// pair of slabs: first = ks2 0 (bias C-init from LDS), second = ks2 1
__device__ __forceinline__ void hidden2_bias(const unsigned char* A, int lane, int hf,
                                             const float* lb_l,
                                             f32x16 (&acc)[4], const f16x8 (&bf)[4][2]) {
    #pragma unroll
    for (int mt = 0; mt < 4; ++mt) {
        f32x16 c16;
        #pragma unroll
        for (int g2 = 0; g2 < 4; ++g2) {
            f32x4 t = *(const f32x4*)(lb_l + 32 * mt + 8 * g2 + 4 * hf);
            c16[4 * g2 + 0] = t[0]; c16[4 * g2 + 1] = t[1];
            c16[4 * g2 + 2] = t[2]; c16[4 * g2 + 3] = t[3];
        }
        f16x8 a0 = lda(A, mt * 2, lane), a1 = lda(A, mt * 2 + 1, lane);
        acc[mt] = mfma32(a1, bf[0][1], mfma32(a0, bf[0][0], c16));
    }
    const unsigned char* B = A + 8192;
    #pragma unroll
    for (int mt = 0; mt < 4; ++mt) {
        f16x8 a0 = lda(B, mt * 2, lane), a1 = lda(B, mt * 2 + 1, lane);
        acc[mt] = mfma32(a1, bf[1][1], mfma32(a0, bf[1][0], acc[mt]));
    }
}

// pair of slabs: ks2 2 then ks2 3 (accumulate)
__device__ __forceinline__ void hidden2_acc(const unsigned char* A, int lane,
                                            f32x16 (&acc)[4], const f16x8 (&bf)[4][2]) {
    #pragma unroll
    for (int mt = 0; mt < 4; ++mt) {
        f16x8 a0 = lda(A, mt * 2, lane), a1 = lda(A, mt * 2 + 1, lane);
        acc[mt] = mfma32(a1, bf[2][1], mfma32(a0, bf[2][0], acc[mt]));
    }
    const unsigned char* B = A + 8192;
    #pragma unroll
    for (int mt = 0; mt < 4; ++mt) {
        f16x8 a0 = lda(B, mt * 2, lane), a1 = lda(B, mt * 2 + 1, lane);
        acc[mt] = mfma32(a1, bf[3][1], mfma32(a0, bf[3][0], acc[mt]));
    }
}

__device__ __forceinline__ float out_dot(const f32x16 (&acc)[4], const float* lwout, int hf) {
    float pt0 = 0.0f;
    #pragma unroll
    for (int mt = 0; mt < 4; ++mt) {
        #pragma unroll
        for (int q = 0; q < 4; ++q) {
            f32x4 w4 = *(const f32x4*)(lwout + 32 * mt + 8 * q + 4 * hf);
            #pragma unroll
            for (int i = 0; i < 4; ++i)
                pt0 = fmaf(tanh_fast(acc[mt][4 * q + i]), w4[i], pt0);
        }
    }
    return pt0 + __shfl_xor(pt0, 32);   // full 128-dot for sample (lane&31)
}

__global__ __launch_bounds__(NTHREADS, 3)
void node_main(const float* __restrict__ tx, const f16* __restrict__ wsw,
               const float* __restrict__ dp_Wout, const float* __restrict__ dp_bout,
               const float* __restrict__ ic_Wout, const float* __restrict__ ic_bout,
               float* __restrict__ out)
{
    __shared__ __align__(16) unsigned char lds_w[2][16384];  // 2-slot group ring
    __shared__ __align__(16) float lds_bias[768];
    __shared__ __align__(16) float lds_wout[2][128];
    __shared__ float lds_bout[2];

    const int tid  = threadIdx.x;
    const int lane = tid & 63;
    const int wv   = tid >> 6;
    const int l31  = lane & 31;
    const int hf   = lane >> 5;
    const int p0   = blockIdx.x * 128;

    const float* bsc = (const float*)(wsw + 2 * MLP_STRIDE);
    const float4* tx4 = (const float4*)tx;

    // ---- one-time LDS copy of bias/Wout/bout (FIXED: strided loop covers all
    //      768 entries; `if (tid<768)` with 256 thr left [256..767] uninit,
    //      which is what killed R18/R19 at 3 blocks/CU) ----
    for (int i = tid; i < 768; i += NTHREADS) lds_bias[i] = bsc[i];
    if (tid < 128) { lds_wout[0][tid] = ic_Wout[tid]; lds_wout[1][tid] = dp_Wout[tid]; }
    if (tid == 0)  { lds_bout[0] = ic_bout[0]; lds_bout[1] = dp_bout[0]; }
    __asm__ __volatile__("" ::: "memory");

    // ---- features for the wave's sample (lane&31) ----
    const int sown = wv * 32 + l31;
    float rA, xA, yA, zA, iA, aA;
    {
        float4 tv = tx4[p0 + sown];
        float xx = tv.y, yy = tv.z, zz = tv.w;
        float rr = sqrtf(fmaf(xx, xx, fmaf(yy, yy, zz * zz)));
        float irs = 1.0f / fmaxf(rr, 1e-8f);
        rA = rr; xA = xx * irs; yA = yy * irs; zA = zz * irs;
        iA = 1.0f / (1.0f + rr);
        aA = 0.5f * tv.x;
    }

    // ---- prologue: stage chain0 G0 (ic slab0) into slot 0 ----
    stage_slab(wsw + MLP_STRIDE, &lds_w[0][0], tid);

    float icv = 0.0f, dsum = 0.0f;
    int p = 0;

    #pragma unroll 1
    for (int c = 0; c < 4; ++c) {
        const f16* wb    = wsw + (c == 0 ? MLP_STRIDE : 0);
        const float* lb  = lds_bias + (c == 0 ? 384 : 0);
        const int mi     = (c == 0) ? 0 : 1;
        const float tn   = (c == 1) ? 0.22540333075851662f
                         : ((c == 2) ? 1.0f : 1.7745966692414834f);   // node+1

        // input-layer B frag (lanes 0..31 hold real data; upper k-half zero)
        f16x8 bfr = {};
        if (lane < 32) {
            if (c == 0) {
                bfr[0] = (f16)rA; bfr[1] = (f16)xA; bfr[2] = (f16)yA;
                bfr[3] = (f16)zA; bfr[4] = (f16)iA; bfr[5] = (f16)1.0f;
            } else {
                bfr[0] = (f16)(aA * tn); bfr[1] = (f16)rA; bfr[2] = (f16)xA;
                bfr[3] = (f16)yA; bfr[4] = (f16)zA; bfr[5] = (f16)iA;
                bfr[6] = (f16)1.0f;
            }
        }

        f32x16 acc[4];
        f16x8 bfrag[4][2];

        // S0: G0 ready; stage G1 (slabs 1,2); compute input layer
        SYNC0;
        stage_slab(wb + 1 * SLAB_F16, &lds_w[p ^ 1][0], tid);
        stage_slab(wb + 2 * SLAB_F16, &lds_w[p ^ 1][0] + 8192, tid);
        input_slab(&lds_w[p][0], lane, bfr, acc);
        frag_build(acc, bfrag);
        p ^= 1;

        // S1: G1 ready; stage G2 (3,4); l0 ks 0,1
        SYNC0;
        stage_slab(wb + 3 * SLAB_F16, &lds_w[p ^ 1][0], tid);
        stage_slab(wb + 4 * SLAB_F16, &lds_w[p ^ 1][0] + 8192, tid);
        hidden2_bias(&lds_w[p][0], lane, hf, lb + 0 * 128, acc, bfrag);
        p ^= 1;

        // S2: G2 ready; stage G3 (5,6); l0 ks 2,3 + frag-build
        SYNC0;
        stage_slab(wb + 5 * SLAB_F16, &lds_w[p ^ 1][0], tid);
        stage_slab(wb + 6 * SLAB_F16, &lds_w[p ^ 1][0] + 8192, tid);
        hidden2_acc(&lds_w[p][0], lane, acc, bfrag);
        frag_build(acc, bfrag);
        p ^= 1;

        // S3: G3 ready; stage G4 (7,8); l1 ks 0,1
        SYNC0;
        stage_slab(wb + 7 * SLAB_F16, &lds_w[p ^ 1][0], tid);
        stage_slab(wb + 8 * SLAB_F16, &lds_w[p ^ 1][0] + 8192, tid);
        hidden2_bias(&lds_w[p][0], lane, hf, lb + 1 * 128, acc, bfrag);
        p ^= 1;

        // S4: G4 ready; stage G5 (9,10); l1 ks 2,3 + frag-build
        SYNC0;
        stage_slab(wb + 9 * SLAB_F16, &lds_w[p ^ 1][0], tid);
        stage_slab(wb + 10 * SLAB_F16, &lds_w[p ^ 1][0] + 8192, tid);
        hidden2_acc(&lds_w[p][0], lane, acc, bfrag);
        frag_build(acc, bfrag);
        p ^= 1;

        // S5: G5 ready; stage G6 (11,12); l2 ks 0,1
        SYNC0;
        stage_slab(wb + 11 * SLAB_F16, &lds_w[p ^ 1][0], tid);
        stage_slab(wb + 12 * SLAB_F16, &lds_w[p ^ 1][0] + 8192, tid);
        hidden2_bias(&lds_w[p][0], lane, hf, lb + 2 * 128, acc, bfrag);
        p ^= 1;

        // S6: G6 ready; stage next chain's G0; l2 ks 2,3
        SYNC0;
        if (c < 3)
            stage_slab(wsw, &lds_w[p ^ 1][0], tid);   // dp base slab 0
        hidden2_acc(&lds_w[p][0], lane, acc, bfrag);
        p ^= 1;

        // output layer from acc regs + LDS-resident Wout/bout
        float val = out_dot(acc, &lds_wout[mi][0], hf) + lds_bout[mi];
        if (c == 0) icv = val;
        else        dsum = fmaf((c == 2) ? (8.0f / 9.0f) : (5.0f / 9.0f), val, dsum);
    }

    if (lane < 32)
        out[p0 + sown] = (icv + aA * dsum) * iA;
}

extern "C" void kernel_launch(void* const* d_in, const int* in_sizes, int n_in,
                              void* d_out, int out_size, void* d_ws, size_t ws_size,
                              hipStream_t stream) {
    const float* tx      = (const float*)d_in[0];
    const float* dp_Win  = (const float*)d_in[1];
    const float* dp_bin  = (const float*)d_in[2];
    const float* dp_Wh   = (const float*)d_in[3];
    const float* dp_bh   = (const float*)d_in[4];
    const float* dp_Wout = (const float*)d_in[5];
    const float* dp_bout = (const float*)d_in[6];
    const float* ic_Win  = (const float*)d_in[7];
    const float* ic_bin  = (const float*)d_in[8];
    const float* ic_Wh   = (const float*)d_in[9];
    const float* ic_bh   = (const float*)d_in[10];
    const float* ic_Wout = (const float*)d_in[11];
    const float* ic_bout = (const float*)d_in[12];
    float* out = (float*)d_out;
    f16* wsw = (f16*)d_ws;

    int n = in_sizes[0] / 4;

    prep_kernel<<<dim3((2 * MLP_STRIDE + 768 + NTHREADS - 1) / NTHREADS), dim3(NTHREADS), 0, stream>>>(
        dp_Win, dp_bin, dp_Wh, dp_bh, ic_Win, ic_bin, ic_Wh, ic_bh, wsw);

    node_main<<<dim3(n / 128), dim3(NTHREADS), 0, stream>>>(
        tx, wsw, dp_Wout, dp_bout, ic_Wout, ic_bout, out);
}

// Round 14
// 224.813 us; speedup vs baseline: 1.0152x; 1.0152x over previous
//
#include <hip/hip_runtime.h>

// NODEModel MFMA fp16, R22: nt=1 + counted-vmcnt (= R18 + bias fix).
// R21 (167.9us) confirmed BOTH: (1) the R18/R19 failures were the
// uninitialized lds_bias[256..767] read (if(tid<768) with 256 thr), fatal
// only at 3 blocks/CU where the third LDS slot held stale bytes; (2) the
// nt=1 3-waves/SIMD structure is a real win (-3.2%, occ 19.5->28.7, VGPR 84
// = no spill, far under the 168 cap -> R18's counted windows were never
// spill-broken). So the two verified orthogonal wins -- nt=1@3blk (R21,
// -5.6us) and counted-vmcnt paired staging (R17, -4.0us) -- can now be
// combined safely: R22 = R18's schedule verbatim (7 sync groups, 3-slot x
// 16KB ring, stage 2 groups ahead, VM4 at S0-S5, VM2/VM0 at S6, prefetch
// never drained mid-loop) + strided bias copy. LDS 53.76KB x3 = 157.5KiB
// <= 160KiB -> 3 blocks/CU holds. Only staging vmem in the loop (bias/
// Wout/bout in LDS; tx retired pre-prologue) -> counted windows exact.

#define NTHREADS 256
#define MLP_STRIDE 53248   // fp16 elems per MLP: 4096 WinA + 3*16384 Wh = 13 slabs
#define WINA_ELEMS 4096
#define SLAB_F16 4096      // 8 KB slab
#define TANH_SCALE 2.8853900817779268f   // 2*log2(e)

typedef _Float16 f16;
typedef f16 f16x8 __attribute__((ext_vector_type(8)));
typedef __fp16 fp16x2 __attribute__((ext_vector_type(2)));
typedef float f32x4 __attribute__((ext_vector_type(4)));
typedef float f32x16 __attribute__((ext_vector_type(16)));

// ---------------- prep: fp32 weights -> fp16 fragment-linear (pre-scaled) ----
// Slab layout (8KB): [mt(4)][kh(2)][lane(64)][j(8)] f16;
//   m = 32*mt + (lane&31), k_slot = base + 16*kh + 8*(lane>>5) + j.
// Hidden slabs: weight k-row = tau(k_slot) so next-layer B comes from acc regs.
__global__ __launch_bounds__(NTHREADS)
void prep_kernel(const float* __restrict__ dp_Win, const float* __restrict__ dp_bin,
                 const float* __restrict__ dp_Wh,  const float* __restrict__ dp_bh,
                 const float* __restrict__ ic_Win, const float* __restrict__ ic_bin,
                 const float* __restrict__ ic_Wh,  const float* __restrict__ ic_bh,
                 f16* __restrict__ wsw)
{
    int e = blockIdx.x * NTHREADS + threadIdx.x;
    if (e >= 2 * MLP_STRIDE + 768) return;
    if (e >= 2 * MLP_STRIDE) {          // scaled hidden biases, fp32
        int idx = e - 2 * MLP_STRIDE;   // [mlp(2)][l(3)][m(128)]
        int mlp = idx / 384, rem = idx % 384;
        const float* bh = mlp ? ic_bh : dp_bh;
        float* bsc = (float*)(wsw + 2 * MLP_STRIDE);
        bsc[idx] = bh[rem] * TANH_SCALE;
        return;
    }
    int mlp = (e >= MLP_STRIDE) ? 1 : 0;   // 0 = dp, 1 = ic
    int r = e - mlp * MLP_STRIDE;
    const float* Win = mlp ? ic_Win : dp_Win;
    const float* bin = mlp ? ic_bin : dp_bin;
    const float* Wh  = mlp ? ic_Wh  : dp_Wh;
    int din = mlp ? 5 : 6;
    float val;
    if (r < WINA_ELEMS) {
        int mt = r >> 10, kh = (r >> 9) & 1, lane = (r >> 3) & 63, j = r & 7;
        int m = mt * 32 + (lane & 31);
        int k = kh * 16 + ((lane >> 5) << 3) + j;           // feature index, natural
        val = (k < din) ? Win[k * 128 + m] : ((k == din) ? bin[m] : 0.0f);
    } else {
        int r2 = r - WINA_ELEMS;
        int l = r2 >> 14, r3 = r2 & 16383;
        int ks = r3 >> 12, mt = (r3 >> 10) & 3, kh = (r3 >> 9) & 1;
        int lane = (r3 >> 3) & 63, j = r3 & 7;
        int m = mt * 32 + (lane & 31);
        int k = ks * 32 + kh * 16 + ((lane >> 5) << 3) + j; // slot 0..127
        // tau: slot k=16t+8h'+j' holds prev-layer unit 16t+8*(j'>>2)+4h'+(j'&3)
        int kt = (k & ~15) | (((k & 7) >> 2) << 3) | (((k >> 3) & 1) << 2) | (k & 3);
        val = Wh[(l * 128 + kt) * 128 + m];
    }
    wsw[e] = (f16)(val * TANH_SCALE);
}

// ---------------- main helpers ----------------
__device__ __forceinline__ float tanh_fast(float x) {
    float e = __builtin_amdgcn_exp2f(x);
    float r = __builtin_amdgcn_rcpf(e + 1.0f);
    return fmaf(-2.0f, r, 1.0f);
}

__device__ __forceinline__ unsigned int tanh2_pk(float x0, float x1) {
    float a0 = __builtin_amdgcn_exp2f(x0) + 1.0f;
    float a1 = __builtin_amdgcn_exp2f(x1) + 1.0f;
    float n2 = -2.0f * __builtin_amdgcn_rcpf(a0 * a1);
    union { fp16x2 h; unsigned int u; } c;
    c.h = __builtin_amdgcn_cvt_pkrtz(fmaf(n2, a1, 1.0f), fmaf(n2, a0, 1.0f));
    return c.u;
}

__device__ __forceinline__ f32x16 mfma32(f16x8 a, f16x8 b, f32x16 c) {
    return __builtin_amdgcn_mfma_f32_32x32x16_f16(a, b, c, 0, 0, 0);
}

__device__ __forceinline__ void stage16(const void* g, void* l) {
    __builtin_amdgcn_global_load_lds((const __attribute__((address_space(1))) void*)g,
                                     (__attribute__((address_space(3))) void*)l, 16, 0, 0);
}

__device__ __forceinline__ void stage_slab(const f16* g, unsigned char* dst, int tid) {
    stage16((const char*)g + tid * 16, dst + tid * 16);
    stage16((const char*)g + 4096 + tid * 16, dst + 4096 + tid * 16);
}

__device__ __forceinline__ f16x8 lda(const unsigned char* A, int idx, int lane) {
    return *(const f16x8*)(A + ((idx * 64 + lane) << 4));
}

// sync: counted vmcnt + lgkmcnt(0) + barrier
#define SYNC(ENC) do { \
    __asm__ __volatile__("" ::: "memory"); \
    __builtin_amdgcn_s_waitcnt(ENC); \
    __builtin_amdgcn_s_barrier(); \
    __asm__ __volatile__("" ::: "memory"); \
} while (0)
#define VM4 0x0074   // vmcnt=4, expcnt=7, lgkmcnt=0
#define VM2 0x0072
#define VM0 0x0070

__device__ __forceinline__ void frag_build(const f32x16 (&acc)[4], f16x8 (&bf)[4][2]) {
    #pragma unroll
    for (int mt = 0; mt < 4; ++mt)
        #pragma unroll
        for (int kh = 0; kh < 2; ++kh) {
            union { f16x8 f; unsigned u[4]; } w;
            #pragma unroll
            for (int q = 0; q < 4; ++q)
                w.u[q] = tanh2_pk(acc[mt][8 * kh + 2 * q],
                                  acc[mt][8 * kh + 2 * q + 1]);
            bf[mt][kh] = w.f;
        }
}

__device__ __forceinline__ void input_slab(const unsigned char* A, int lane,
                                           const f16x8 bfr, f32x16 (&acc)[4]) {
    const f32x16 z16 = {0.f,0.f,0.f,0.f, 0.f,0.f,0.f,0.f, 0.f,0.f,0.f,0.f, 0.f,0.f,0.f,0.f};
    #pragma unroll
    for (int mt = 0; mt < 4; ++mt) {
        f16x8 a0 = lda(A, mt * 2, lane);
        acc[mt] = mfma32(a0, bfr, z16);
    }
}

// pair of slabs: first = ks2 0 (bias C-init from LDS), second = ks2 1
__device__ __forceinline__ void hidden2_bias(const unsigned char* A, int lane, int hf,
                                             const float* lb_l,
                                             f32x16 (&acc)[4], const f16x8 (&bf)[4][2]) {
    #pragma unroll
    for (int mt = 0; mt < 4; ++mt) {
        f32x16 c16;
        #pragma unroll
        for (int g2 = 0; g2 < 4; ++g2) {
            f32x4 t = *(const f32x4*)(lb_l + 32 * mt + 8 * g2 + 4 * hf);
            c16[4 * g2 + 0] = t[0]; c16[4 * g2 + 1] = t[1];
            c16[4 * g2 + 2] = t[2]; c16[4 * g2 + 3] = t[3];
        }
        f16x8 a0 = lda(A, mt * 2, lane), a1 = lda(A, mt * 2 + 1, lane);
        acc[mt] = mfma32(a1, bf[0][1], mfma32(a0, bf[0][0], c16));
    }
    const unsigned char* B = A + 8192;
    #pragma unroll
    for (int mt = 0; mt < 4; ++mt) {
        f16x8 a0 = lda(B, mt * 2, lane), a1 = lda(B, mt * 2 + 1, lane);
        acc[mt] = mfma32(a1, bf[1][1], mfma32(a0, bf[1][0], acc[mt]));
    }
}

// pair of slabs: ks2 2 then ks2 3 (accumulate)
__device__ __forceinline__ void hidden2_acc(const unsigned char* A, int lane,
                                            f32x16 (&acc)[4], const f16x8 (&bf)[4][2]) {
    #pragma unroll
    for (int mt = 0; mt < 4; ++mt) {
        f16x8 a0 = lda(A, mt * 2, lane), a1 = lda(A, mt * 2 + 1, lane);
        acc[mt] = mfma32(a1, bf[2][1], mfma32(a0, bf[2][0], acc[mt]));
    }
    const unsigned char* B = A + 8192;
    #pragma unroll
    for (int mt = 0; mt < 4; ++mt) {
        f16x8 a0 = lda(B, mt * 2, lane), a1 = lda(B, mt * 2 + 1, lane);
        acc[mt] = mfma32(a1, bf[3][1], mfma32(a0, bf[3][0], acc[mt]));
    }
}

__device__ __forceinline__ float out_dot(const f32x16 (&acc)[4], const float* lwout, int hf) {
    float pt0 = 0.0f;
    #pragma unroll
    for (int mt = 0; mt < 4; ++mt) {
        #pragma unroll
        for (int q = 0; q < 4; ++q) {
            f32x4 w4 = *(const f32x4*)(lwout + 32 * mt + 8 * q + 4 * hf);
            #pragma unroll
            for (int i = 0; i < 4; ++i)
                pt0 = fmaf(tanh_fast(acc[mt][4 * q + i]), w4[i], pt0);
        }
    }
    return pt0 + __shfl_xor(pt0, 32);   // full 128-dot for sample (lane&31)
}

__global__ __launch_bounds__(NTHREADS, 3)
void node_main(const float* __restrict__ tx, const f16* __restrict__ wsw,
               const float* __restrict__ dp_Wout, const float* __restrict__ dp_bout,
               const float* __restrict__ ic_Wout, const float* __restrict__ ic_bout,
               float* __restrict__ out)
{
    __shared__ __align__(16) unsigned char lds_w[3][16384];  // 3-slot paired ring
    __shared__ __align__(16) float lds_bias[768];
    __shared__ __align__(16) float lds_wout[2][128];
    __shared__ float lds_bout[2];

    const int tid  = threadIdx.x;
    const int lane = tid & 63;
    const int wv   = tid >> 6;
    const int l31  = lane & 31;
    const int hf   = lane >> 5;
    const int p0   = blockIdx.x * 128;

    const float* bsc = (const float*)(wsw + 2 * MLP_STRIDE);
    const float4* tx4 = (const float4*)tx;

    // ---- one-time LDS copy of bias/Wout/bout (strided: covers all 768;
    //      the old `if (tid<768)` left [256..767] uninit = R18/R19 killer) ----
    for (int i = tid; i < 768; i += NTHREADS) lds_bias[i] = bsc[i];
    if (tid < 128) { lds_wout[0][tid] = ic_Wout[tid]; lds_wout[1][tid] = dp_Wout[tid]; }
    if (tid == 0)  { lds_bout[0] = ic_bout[0]; lds_bout[1] = dp_bout[0]; }
    __asm__ __volatile__("" ::: "memory");

    // ---- features for the wave's sample (lane&31); loads retire pre-prologue --
    const int sown = wv * 32 + l31;
    float rA, xA, yA, zA, iA, aA;
    {
        float4 tv = tx4[p0 + sown];
        float xx = tv.y, yy = tv.z, zz = tv.w;
        float rr = sqrtf(fmaf(xx, xx, fmaf(yy, yy, zz * zz)));
        float irs = 1.0f / fmaxf(rr, 1e-8f);
        rA = rr; xA = xx * irs; yA = yy * irs; zA = zz * irs;
        iA = 1.0f / (1.0f + rr);
        aA = 0.5f * tv.x;
    }

    // ---- prologue staging: chain0 G0 (ic slab0 -> slot0) + G1 (slabs1,2 -> slot1)
    {
        const f16* ic = wsw + MLP_STRIDE;
        stage_slab(ic + 0 * SLAB_F16, &lds_w[0][0], tid);
        stage_slab(ic + 1 * SLAB_F16, &lds_w[1][0], tid);
        stage_slab(ic + 2 * SLAB_F16, &lds_w[1][0] + 8192, tid);
    }

    float icv = 0.0f, dsum = 0.0f;

    #pragma unroll 1
    for (int c = 0; c < 4; ++c) {
        const f16* wb    = wsw + (c == 0 ? MLP_STRIDE : 0);
        const float* lb  = lds_bias + (c == 0 ? 384 : 0);
        const int mi     = (c == 0) ? 0 : 1;
        const float tn   = (c == 1) ? 0.22540333075851662f
                         : ((c == 2) ? 1.0f : 1.7745966692414834f);   // node+1
        const int s0     = (c == 3) ? 0 : c;   // c % 3

        // slot base for group g (g compile-time; s0 runtime scalar)
        auto SLOT = [&](int g) -> unsigned char* {
            int t = s0 + g;
            t = (t >= 6) ? t - 6 : t;
            t = (t >= 3) ? t - 3 : t;
            return &lds_w[0][0] + t * 16384;
        };

        // input-layer B frag (lanes 0..31 hold real data; upper k-half zero)
        f16x8 bfr = {};
        if (lane < 32) {
            if (c == 0) {
                bfr[0] = (f16)rA; bfr[1] = (f16)xA; bfr[2] = (f16)yA;
                bfr[3] = (f16)zA; bfr[4] = (f16)iA; bfr[5] = (f16)1.0f;
            } else {
                bfr[0] = (f16)(aA * tn); bfr[1] = (f16)rA; bfr[2] = (f16)xA;
                bfr[3] = (f16)yA; bfr[4] = (f16)zA; bfr[5] = (f16)iA;
                bfr[6] = (f16)1.0f;
            }
        }

        f32x16 acc[4];
        f16x8 bfrag[4][2];

        // S0: need G0; G1 stays in flight
        SYNC(VM4);
        stage_slab(wb + 3 * SLAB_F16, SLOT(2), tid);
        stage_slab(wb + 4 * SLAB_F16, SLOT(2) + 8192, tid);
        input_slab(SLOT(0), lane, bfr, acc);
        frag_build(acc, bfrag);

        // S1: need G1 (slabs 1,2 = l0 ks 0,1)
        SYNC(VM4);
        stage_slab(wb + 5 * SLAB_F16, SLOT(3), tid);
        stage_slab(wb + 6 * SLAB_F16, SLOT(3) + 8192, tid);
        hidden2_bias(SLOT(1), lane, hf, lb + 0 * 128, acc, bfrag);

        // S2: need G2 (slabs 3,4 = l0 ks 2,3) + frag-build
        SYNC(VM4);
        stage_slab(wb + 7 * SLAB_F16, SLOT(4), tid);
        stage_slab(wb + 8 * SLAB_F16, SLOT(4) + 8192, tid);
        hidden2_acc(SLOT(2), lane, acc, bfrag);
        frag_build(acc, bfrag);

        // S3: need G3 (slabs 5,6 = l1 ks 0,1)
        SYNC(VM4);
        stage_slab(wb + 9 * SLAB_F16, SLOT(5), tid);
        stage_slab(wb + 10 * SLAB_F16, SLOT(5) + 8192, tid);
        hidden2_bias(SLOT(3), lane, hf, lb + 1 * 128, acc, bfrag);

        // S4: need G4 (slabs 7,8 = l1 ks 2,3) + frag-build
        SYNC(VM4);
        stage_slab(wb + 11 * SLAB_F16, SLOT(6), tid);
        stage_slab(wb + 12 * SLAB_F16, SLOT(6) + 8192, tid);
        hidden2_acc(SLOT(4), lane, acc, bfrag);
        frag_build(acc, bfrag);

        // S5: need G5 (slabs 9,10 = l2 ks 0,1); stage next chain's G0
        SYNC(VM4);
        if (c < 3)
            stage_slab(wsw + 0 * SLAB_F16, SLOT(7), tid);
        hidden2_bias(SLOT(5), lane, hf, lb + 2 * 128, acc, bfrag);

        // S6: need G6 (slabs 11,12 = l2 ks 2,3); next-chain G0 (2 loads) may
        // remain in flight (in-order retirement => vmcnt(2) proves G6 done)
        if (c < 3) { SYNC(VM2); } else { SYNC(VM0); }
        if (c < 3) {
            stage_slab(wsw + 1 * SLAB_F16, SLOT(8), tid);
            stage_slab(wsw + 2 * SLAB_F16, SLOT(8) + 8192, tid);
        }
        hidden2_acc(SLOT(6), lane, acc, bfrag);

        // output layer from acc regs + LDS-resident Wout/bout
        float val = out_dot(acc, &lds_wout[mi][0], hf) + lds_bout[mi];
        if (c == 0) icv = val;
        else        dsum = fmaf((c == 2) ? (8.0f / 9.0f) : (5.0f / 9.0f), val, dsum);
    }

    if (lane < 32)
        out[p0 + sown] = (icv + aA * dsum) * iA;
}

extern "C" void kernel_launch(void* const* d_in, const int* in_sizes, int n_in,
                              void* d_out, int out_size, void* d_ws, size_t ws_size,
                              hipStream_t stream) {
    const float* tx      = (const float*)d_in[0];
    const float* dp_Win  = (const float*)d_in[1];
    const float* dp_bin  = (const float*)d_in[2];
    const float* dp_Wh   = (const float*)d_in[3];
    const float* dp_bh   = (const float*)d_in[4];
    const float* dp_Wout = (const float*)d_in[5];
    const float* dp_bout = (const float*)d_in[6];
    const float* ic_Win  = (const float*)d_in[7];
    const float* ic_bin  = (const float*)d_in[8];
    const float* ic_Wh   = (const float*)d_in[9];
    const float* ic_bh   = (const float*)d_in[10];
    const float* ic_Wout = (const float*)d_in[11];
    const float* ic_bout = (const float*)d_in[12];
    float* out = (float*)d_out;
    f16* wsw = (f16*)d_ws;

    int n = in_sizes[0] / 4;

    prep_kernel<<<dim3((2 * MLP_STRIDE + 768 + NTHREADS - 1) / NTHREADS), dim3(NTHREADS), 0, stream>>>(
        dp_Win, dp_bin, dp_Wh, dp_bh, ic_Win, ic_bin, ic_Wh, ic_bh, wsw);

    node_main<<<dim3(n / 128), dim3(NTHREADS), 0, stream>>>(
        tx, wsw, dp_Wout, dp_bout, ic_Wout, ic_bout, out);
}